// Round 1
// baseline (3221.061 us; speedup 1.0000x reference)
//
#include <hip/hip_runtime.h>

// CLDice loss on MI355X.
// logits: (2,2,192,192,192) f32, targets: (2,192,192,192) i32, out: scalar f32.
// soft_erode = 3^3 min-pool (SAME => valid-window), soft_dilate = 3^3 max-pool.
// Workspace layout (floats): [sums:16][img:N][e1:N][tmp:N][skel:N], N=14,155,776
// => needs ws_size >= 16*4 + 4*N*4 bytes ~= 226.6 MB.

#define ZD 192
#define YD 192
#define XD 192
#define NB 2
constexpr int VOL  = ZD * YD * XD;      // 7,077,888
constexpr int NTOT = NB * VOL;          // 14,155,776 (divisible by 4)

// ---------------- prep: img = sigmoid(l1-l0)  or  (targets==1) ----------------
__global__ void prep_kernel(const float* __restrict__ logits,
                            const int* __restrict__ targets,
                            float* __restrict__ img, int mode)
{
    int i4 = blockIdx.x * blockDim.x + threadIdx.x;
    if (i4 >= NTOT / 4) return;
    int i = i4 * 4;
    float4 r;
    if (mode == 0) {
        int b = i / VOL, v = i - b * VOL;   // VOL%4==0 so all 4 share b
        float4 l0 = *(const float4*)(logits + (size_t)(b * 2    ) * VOL + v);
        float4 l1 = *(const float4*)(logits + (size_t)(b * 2 + 1) * VOL + v);
        r.x = 1.f / (1.f + expf(l0.x - l1.x));
        r.y = 1.f / (1.f + expf(l0.y - l1.y));
        r.z = 1.f / (1.f + expf(l0.z - l1.z));
        r.w = 1.f / (1.f + expf(l0.w - l1.w));
    } else {
        int4 t = *(const int4*)(targets + i);
        r.x = (t.x == 1) ? 1.f : 0.f;
        r.y = (t.y == 1) ? 1.f : 0.f;
        r.z = (t.z == 1) ? 1.f : 0.f;
        r.w = (t.w == 1) ? 1.f : 0.f;
    }
    *(float4*)(img + i) = r;
}

// ---------------- 3x3x3 min/max pool, z-streaming separable ----------------
template <bool ISMIN>
__device__ inline float MM(float a, float b) { return ISMIN ? fminf(a, b) : fmaxf(a, b); }

template <bool ISMIN>
__global__ __launch_bounds__(256)
void pool_kernel(const float* __restrict__ in, float* __restrict__ out)
{
    constexpr int XT = 64, YT = 4, ZCH = 24;
    constexpr int NXT = XD / XT;            // 3 x-tiles
    constexpr int LW  = XT + 2;             // 66 halo'd cols
    constexpr int NLD = (YT + 2) * LW;      // 396 halo'd plane elems
    const float ID = ISMIN ? __builtin_inff() : -__builtin_inff();

    __shared__ float sm[2][YT + 2][XT + 4]; // stride 68

    int tx = threadIdx.x, ty = threadIdx.y;
    int t  = ty * XT + tx;
    int xt = blockIdx.x % NXT, yt = blockIdx.x / NXT;
    int x0 = xt * XT, y0 = yt * YT;
    int z0 = blockIdx.y * ZCH;
    const float* inb  = in  + (size_t)blockIdx.z * VOL;
    float*       outb = out + (size_t)blockIdx.z * VOL;

    // each thread fills up to 2 of the 396 halo'd plane entries
    int i0 = t, i1 = t + 256;
    int dy0 = i0 / LW, dx0 = i0 - dy0 * LW;
    int dy1 = i1 / LW, dx1 = i1 - dy1 * LW;
    int gy0 = y0 - 1 + dy0, gx0 = x0 - 1 + dx0;
    int gy1 = y0 - 1 + dy1, gx1 = x0 - 1 + dx1;
    bool ok0 = (gy0 >= 0 && gy0 < YD && gx0 >= 0 && gx0 < XD);
    bool ok1 = (i1 < NLD) && (gy1 >= 0 && gy1 < YD && gx1 >= 0 && gx1 < XD);
    int off0 = gy0 * XD + gx0;
    int off1 = gy1 * XD + gx1;

    float pp = ID, p = ID;   // z ring: s(z-2), s(z-1)
    #pragma unroll 1
    for (int zp = z0 - 1; zp <= z0 + ZCH; ++zp) {
        int buf = (zp - (z0 - 1)) & 1;
        float a0 = ID, a1 = ID;
        if (zp >= 0 && zp < ZD) {
            const float* pl = inb + (size_t)zp * (YD * XD);
            if (ok0) a0 = pl[off0];
            if (ok1) a1 = pl[off1];
        }
        sm[buf][dy0][dx0] = a0;
        if (i1 < NLD) sm[buf][dy1][dx1] = a1;
        __syncthreads();
        // xy 3x3 pool of plane zp
        float r0 = MM<ISMIN>(sm[buf][ty    ][tx], MM<ISMIN>(sm[buf][ty    ][tx + 1], sm[buf][ty    ][tx + 2]));
        float r1 = MM<ISMIN>(sm[buf][ty + 1][tx], MM<ISMIN>(sm[buf][ty + 1][tx + 1], sm[buf][ty + 1][tx + 2]));
        float r2 = MM<ISMIN>(sm[buf][ty + 2][tx], MM<ISMIN>(sm[buf][ty + 2][tx + 1], sm[buf][ty + 2][tx + 2]));
        float cur = MM<ISMIN>(r0, MM<ISMIN>(r1, r2));
        int zc = zp - 1;
        if (zc >= z0 && zc < z0 + ZCH) {
            outb[((size_t)zc * YD + (y0 + ty)) * XD + (x0 + tx)] = MM<ISMIN>(pp, MM<ISMIN>(p, cur));
        }
        pp = p; p = cur;
        // double-buffered: the single barrier above per iter also protects reuse
    }
}

// ---------------- skel = relu(img - open) ----------------
__global__ void skel_init_kernel(const float* __restrict__ img,
                                 const float* __restrict__ opn,
                                 float* __restrict__ skel)
{
    int i4 = blockIdx.x * blockDim.x + threadIdx.x;
    if (i4 >= NTOT / 4) return;
    int i = i4 * 4;
    float4 a = *(const float4*)(img + i);
    float4 o = *(const float4*)(opn + i);
    float4 r;
    r.x = fmaxf(a.x - o.x, 0.f);
    r.y = fmaxf(a.y - o.y, 0.f);
    r.z = fmaxf(a.z - o.z, 0.f);
    r.w = fmaxf(a.w - o.w, 0.f);
    *(float4*)(skel + i) = r;
}

// ---------------- delta = relu(e1 - d); skel += relu(delta - skel*delta) ----------------
__global__ void skel_update_kernel(const float* __restrict__ e1,
                                   const float* __restrict__ d,
                                   float* __restrict__ skel)
{
    int i4 = blockIdx.x * blockDim.x + threadIdx.x;
    if (i4 >= NTOT / 4) return;
    int i = i4 * 4;
    float4 e  = *(const float4*)(e1 + i);
    float4 dd = *(const float4*)(d + i);
    float4 s  = *(float4*)(skel + i);
    float t;
    t = fmaxf(e.x - dd.x, 0.f); s.x = s.x + fmaxf(t - s.x * t, 0.f);
    t = fmaxf(e.y - dd.y, 0.f); s.y = s.y + fmaxf(t - s.y * t, 0.f);
    t = fmaxf(e.z - dd.z, 0.f); s.z = s.z + fmaxf(t - s.z * t, 0.f);
    t = fmaxf(e.w - dd.w, 0.f); s.w = s.w + fmaxf(t - s.w * t, 0.f);
    *(float4*)(skel + i) = s;
}

// ---------------- reduction: dot(skel, weight) and sum(skel) ----------------
// mode 0: weight = (targets==1) -> sums[0],[1];  mode 1: weight = sigmoid(l1-l0) -> sums[2],[3]
__global__ void reduce_kernel(const float* __restrict__ skel,
                              const float* __restrict__ logits,
                              const int* __restrict__ targets,
                              float* __restrict__ sums, int mode)
{
    float sd = 0.f, ss = 0.f;
    int n4 = NTOT / 4;
    for (int i4 = blockIdx.x * blockDim.x + threadIdx.x; i4 < n4;
         i4 += gridDim.x * blockDim.x) {
        int i = i4 * 4;
        float4 sk = *(const float4*)(skel + i);
        float wx, wy, wz, ww;
        if (mode == 0) {
            int4 tt = *(const int4*)(targets + i);
            wx = (tt.x == 1) ? 1.f : 0.f;
            wy = (tt.y == 1) ? 1.f : 0.f;
            wz = (tt.z == 1) ? 1.f : 0.f;
            ww = (tt.w == 1) ? 1.f : 0.f;
        } else {
            int b = i / VOL, v = i - b * VOL;
            float4 l0 = *(const float4*)(logits + (size_t)(b * 2    ) * VOL + v);
            float4 l1 = *(const float4*)(logits + (size_t)(b * 2 + 1) * VOL + v);
            wx = 1.f / (1.f + expf(l0.x - l1.x));
            wy = 1.f / (1.f + expf(l0.y - l1.y));
            wz = 1.f / (1.f + expf(l0.z - l1.z));
            ww = 1.f / (1.f + expf(l0.w - l1.w));
        }
        sd += sk.x * wx + sk.y * wy + sk.z * wz + sk.w * ww;
        ss += sk.x + sk.y + sk.z + sk.w;
    }
    #pragma unroll
    for (int o = 32; o; o >>= 1) {
        sd += __shfl_down(sd, o, 64);
        ss += __shfl_down(ss, o, 64);
    }
    __shared__ float red[4][2];
    int lane = threadIdx.x & 63, w = threadIdx.x >> 6;
    if (lane == 0) { red[w][0] = sd; red[w][1] = ss; }
    __syncthreads();
    if (threadIdx.x == 0) {
        float d = red[0][0] + red[1][0] + red[2][0] + red[3][0];
        float s = red[0][1] + red[1][1] + red[2][1] + red[3][1];
        atomicAdd(&sums[2 * mode + 0], d);
        atomicAdd(&sums[2 * mode + 1], s);
    }
}

// ---------------- final scalar ----------------
__global__ void final_kernel(const float* __restrict__ sums, float* __restrict__ out)
{
    float tprec = (sums[0] + 1.f) / (sums[1] + 1.f);
    float tsens = (sums[2] + 1.f) / (sums[3] + 1.f);
    float cl = 2.f * tprec * tsens / (tprec + tsens + 1e-7f);
    out[0] = 1.f - cl;
}

extern "C" void kernel_launch(void* const* d_in, const int* in_sizes, int n_in,
                              void* d_out, int out_size, void* d_ws, size_t ws_size,
                              hipStream_t stream)
{
    const float* logits  = (const float*)d_in[0];
    const int*   targets = (const int*)d_in[1];
    float* out  = (float*)d_out;

    float* sums = (float*)d_ws;
    float* img  = sums + 16;
    float* e1   = img + NTOT;
    float* tmp  = e1 + NTOT;
    float* skel = tmp + NTOT;

    hipMemsetAsync(sums, 0, 16 * sizeof(float), stream);

    dim3 pgrid(3 * (YD / 4), ZD / 24, NB);  // (144, 8, 2)
    dim3 pblock(64, 4, 1);
    int egrid = (NTOT / 4 + 255) / 256;     // 13,824

    for (int field = 0; field < 2; ++field) {
        // img = source field
        prep_kernel<<<egrid, 256, 0, stream>>>(logits, targets, img, field);
        // open(img): erode -> tmp, dilate -> e1 ; skel = relu(img - open)
        pool_kernel<true ><<<pgrid, pblock, 0, stream>>>(img, tmp);
        pool_kernel<false><<<pgrid, pblock, 0, stream>>>(tmp, e1);
        skel_init_kernel<<<egrid, 256, 0, stream>>>(img, e1, skel);

        float* pimg = img;
        float* pe1  = e1;
        for (int it = 0; it < 10; ++it) {
            pool_kernel<true ><<<pgrid, pblock, 0, stream>>>(pimg, pe1); // e1 = erode(img)
            pool_kernel<true ><<<pgrid, pblock, 0, stream>>>(pe1, tmp);  // tmp = erode(e1)
            pool_kernel<false><<<pgrid, pblock, 0, stream>>>(tmp, pimg); // d = dilate(tmp) (old img is free)
            skel_update_kernel<<<egrid, 256, 0, stream>>>(pe1, pimg, skel);
            float* sw = pimg; pimg = pe1; pe1 = sw;                      // img <- e1
        }
        reduce_kernel<<<2048, 256, 0, stream>>>(skel, logits, targets, sums, field);
    }
    final_kernel<<<1, 1, 0, stream>>>(sums, out);
}

// Round 2
// 1906.532 us; speedup vs baseline: 1.6895x; 1.6895x over previous
//
#include <hip/hip_runtime.h>

// CLDice loss, fused pipeline.
// Identity: with a_k = erode^k(img):
//   skel = 0
//   for k = 0..10:  delta = relu(a_k - dilate(erode(a_k)));  skel += relu(delta - skel*delta)
// One fused kernel per k: reads a_k (+skel), writes a_{k+1} (+skel).
// k=10 skips all writes and accumulates the two global sums instead.
// Workspace floats: [sums:16][A:N][B:N][skel:N], N = 14,155,776 (~170 MB).

#define ZD 192
#define YD 192
#define XD 192
#define NB 2
constexpr int PLANE = YD * XD;
constexpr int VOL   = ZD * PLANE;       // 7,077,888
constexpr int NTOT  = NB * VOL;         // 14,155,776

constexpr int XT = 64, YT = 8, ZCH = 48;
constexpr int IW = XT + 4, IH = YT + 4; // 68 x 12 img halo plane (+-2)
constexpr int SW = XT + 2, SH = YT + 2; // 66 x 10 s1/b plane (+-1)
constexpr int NIMG = IW * IH;           // 816
constexpr int NS   = SW * SH;           // 660
#define PINF __builtin_inff()

// ---------------- prep: img = sigmoid(l1-l0)  or  (targets==1) ----------------
__global__ void prep_kernel(const float* __restrict__ logits,
                            const int* __restrict__ targets,
                            float* __restrict__ img, int mode)
{
    int i4 = blockIdx.x * blockDim.x + threadIdx.x;
    if (i4 >= NTOT / 4) return;
    int i = i4 * 4;
    float4 r;
    if (mode == 0) {
        int b = i / VOL, v = i - b * VOL;   // VOL%4==0 so all 4 share b
        float4 l0 = *(const float4*)(logits + (size_t)(b * 2    ) * VOL + v);
        float4 l1 = *(const float4*)(logits + (size_t)(b * 2 + 1) * VOL + v);
        r.x = 1.f / (1.f + expf(l0.x - l1.x));
        r.y = 1.f / (1.f + expf(l0.y - l1.y));
        r.z = 1.f / (1.f + expf(l0.z - l1.z));
        r.w = 1.f / (1.f + expf(l0.w - l1.w));
    } else {
        int4 t = *(const int4*)(targets + i);
        r.x = (t.x == 1) ? 1.f : 0.f;
        r.y = (t.y == 1) ? 1.f : 0.f;
        r.z = (t.z == 1) ? 1.f : 0.f;
        r.w = (t.w == 1) ? 1.f : 0.f;
    }
    *(float4*)(img + i) = r;
}

// ---------------- fused: b = erode(img); d = dilate(b); skel update ----------------
// z-streaming: per step zi we load img(zi), compute s1(zi)=xymin3(img(zi)),
// b(zi-1)=zmin3(s1), s2(zi-1)=xymax3(b), emit zo=zi-2 with d(zo)=zmax3(s2).
__global__ __launch_bounds__(512)
void fused_kernel(const float* __restrict__ img_in,
                  float* __restrict__ img_out,
                  float* __restrict__ skel,
                  const float* __restrict__ logits,
                  const int* __restrict__ targets,
                  float* __restrict__ sums,
                  int kidx, int last, int field)
{
    __shared__ float simg[NIMG];
    __shared__ float s1[3][NS];
    __shared__ float sb[NS];
    __shared__ float red[8][2];

    const int tx = threadIdx.x, ty = threadIdx.y;
    const int tid = ty * XT + tx;
    const int xt = blockIdx.x % 3, yt = blockIdx.x / 3;
    const int x0 = xt * XT, y0 = yt * YT;
    const int z0 = blockIdx.y * ZCH;
    const int bb = blockIdx.z;
    const float* inb  = img_in  + (size_t)bb * VOL;
    float*       outb = img_out + (size_t)bb * VOL;
    float*       skb  = skel    + (size_t)bb * VOL;

    // img halo-plane load map (816 entries, <=2 per thread)
    const int r0 = tid / IW, c0 = tid % IW;
    const int l1i = tid + 512;
    const int r1 = l1i / IW, c1 = l1i % IW;
    const int gy0 = y0 - 2 + r0, gx0 = x0 - 2 + c0;
    const int gy1 = y0 - 2 + r1, gx1 = x0 - 2 + c1;
    const bool ok0 = (gy0 >= 0 && gy0 < YD && gx0 >= 0 && gx0 < XD);
    const bool ok1 = (l1i < NIMG) && (gy1 >= 0 && gy1 < YD && gx1 >= 0 && gx1 < XD);
    const int off0 = gy0 * XD + gx0, off1 = gy1 * XD + gx1;

    // s1/b plane map (660 entries, <=2 per thread)
    const int e1 = tid + 512;
    const int si0 = tid / SW, sj0 = tid % SW;
    const int si1 = e1 / SW, sj1 = e1 % SW;
    const bool bok0 = (y0 - 1 + si0 >= 0 && y0 - 1 + si0 < YD &&
                       x0 - 1 + sj0 >= 0 && x0 - 1 + sj0 < XD);
    const bool bok1 = (e1 < NS) && (y0 - 1 + si1 >= 0 && y0 - 1 + si1 < YD &&
                                    x0 - 1 + sj1 >= 0 && x0 - 1 + sj1 < XD);

    float s2p1 = -PINF, s2p2 = -PINF;   // s2(zi-2), s2(zi-3)
    float icp1 = 0.f, icp2 = 0.f;       // img center (zi-1), (zi-2)
    float bcp1 = 0.f;                   // b center (zi-2)
    float sd = 0.f, ss = 0.f;           // reduction accumulators (last only)

    for (int s = 0; s < ZCH + 4; ++s) {
        const int zi = z0 - 2 + s;
        // stage 1: load img plane zi (OOB => +inf, erode identity)
        float a0 = PINF, a1 = PINF;
        if (zi >= 0 && zi < ZD) {
            const float* pl = inb + (size_t)zi * PLANE;
            if (ok0) a0 = pl[off0];
            if (ok1) a1 = pl[off1];
        }
        simg[tid] = a0;
        if (l1i < NIMG) simg[l1i] = a1;
        __syncthreads();
        // stage 2: s1(zi) = xy-min3 of img(zi), region 66x10
        float* s1w = s1[s % 3];
        {
            const float* p = simg + si0 * IW + sj0;
            float m = fminf(fminf(p[0], p[1]), p[2]);
            m = fminf(m, fminf(fminf(p[IW], p[IW + 1]), p[IW + 2]));
            m = fminf(m, fminf(fminf(p[2 * IW], p[2 * IW + 1]), p[2 * IW + 2]));
            s1w[tid] = m;
        }
        if (e1 < NS) {
            const float* p = simg + si1 * IW + sj1;
            float m = fminf(fminf(p[0], p[1]), p[2]);
            m = fminf(m, fminf(fminf(p[IW], p[IW + 1]), p[IW + 2]));
            m = fminf(m, fminf(fminf(p[2 * IW], p[2 * IW + 1]), p[2 * IW + 2]));
            s1w[e1] = m;
        }
        const float ic = simg[(ty + 2) * IW + tx + 2];
        __syncthreads();
        // stage 3: b(zi-1) = min over all 3 s1 slots; force -inf where the
        // b coordinate is outside the volume (dilate must not see it)
        if (s >= 1) {
            float m0 = fminf(fminf(s1[0][tid], s1[1][tid]), s1[2][tid]);
            sb[tid] = bok0 ? m0 : -PINF;
            if (e1 < NS) {
                float m1 = fminf(fminf(s1[0][e1], s1[1][e1]), s1[2][e1]);
                sb[e1] = bok1 ? m1 : -PINF;
            }
        }
        __syncthreads();
        // stage 4: s2(zi-1) = xy-max3 of b at center; -inf if plane OOB in z
        const int zb = zi - 1;
        float s2n = -PINF;
        if (s >= 1 && zb >= 0 && zb < ZD) {
            const float* p = sb + ty * SW + tx;
            float m = fmaxf(fmaxf(p[0], p[1]), p[2]);
            m = fmaxf(m, fmaxf(fmaxf(p[SW], p[SW + 1]), p[SW + 2]));
            m = fmaxf(m, fmaxf(fmaxf(p[2 * SW], p[2 * SW + 1]), p[2 * SW + 2]));
            s2n = m;
        }
        const float bc = (s >= 1) ? sb[(ty + 1) * SW + tx + 1] : 0.f;
        // emit zo = zi-2
        const int zo = zi - 2;
        if (zo >= z0) {
            const float d = fmaxf(s2p2, fmaxf(s2p1, s2n));
            const float delta = fmaxf(icp2 - d, 0.f);
            const size_t idx = (size_t)zo * PLANE + (y0 + ty) * XD + (x0 + tx);
            float sv;
            if (kidx == 0) sv = delta;
            else { const float sk = skb[idx]; sv = sk + fmaxf(delta - sk * delta, 0.f); }
            if (!last) {
                skb[idx]  = sv;
                outb[idx] = bcp1;   // a_{k+1}(zo) = b(zo)
            } else {
                float w;
                if (field == 0) {
                    w = (targets[(size_t)bb * VOL + idx] == 1) ? 1.f : 0.f;
                } else {
                    const float l0v = logits[(size_t)(bb * 2    ) * VOL + idx];
                    const float l1v = logits[(size_t)(bb * 2 + 1) * VOL + idx];
                    w = 1.f / (1.f + expf(l0v - l1v));
                }
                sd += sv * w;
                ss += sv;
            }
        }
        s2p2 = s2p1; s2p1 = s2n;
        icp2 = icp1; icp1 = ic;
        bcp1 = bc;
    }

    if (last) {
        #pragma unroll
        for (int o = 32; o; o >>= 1) {
            sd += __shfl_down(sd, o, 64);
            ss += __shfl_down(ss, o, 64);
        }
        if ((tid & 63) == 0) { red[ty][0] = sd; red[ty][1] = ss; }
        __syncthreads();
        if (tid == 0) {
            float a = 0.f, b2 = 0.f;
            #pragma unroll
            for (int i = 0; i < 8; ++i) { a += red[i][0]; b2 += red[i][1]; }
            atomicAdd(&sums[2 * field + 0], a);
            atomicAdd(&sums[2 * field + 1], b2);
        }
    }
}

// ---------------- final scalar ----------------
__global__ void final_kernel(const float* __restrict__ sums, float* __restrict__ out)
{
    float tprec = (sums[0] + 1.f) / (sums[1] + 1.f);
    float tsens = (sums[2] + 1.f) / (sums[3] + 1.f);
    float cl = 2.f * tprec * tsens / (tprec + tsens + 1e-7f);
    out[0] = 1.f - cl;
}

extern "C" void kernel_launch(void* const* d_in, const int* in_sizes, int n_in,
                              void* d_out, int out_size, void* d_ws, size_t ws_size,
                              hipStream_t stream)
{
    const float* logits  = (const float*)d_in[0];
    const int*   targets = (const int*)d_in[1];
    float* out  = (float*)d_out;

    float* sums = (float*)d_ws;
    float* A    = sums + 16;
    float* B    = A + NTOT;
    float* SK   = B + NTOT;

    hipMemsetAsync(sums, 0, 16 * sizeof(float), stream);

    dim3 fgrid(3 * (YD / YT), ZD / ZCH, NB);   // (72, 4, 2)
    dim3 fblock(XT, YT, 1);                    // 512 threads
    int egrid = (NTOT / 4 + 255) / 256;

    for (int field = 0; field < 2; ++field) {
        prep_kernel<<<egrid, 256, 0, stream>>>(logits, targets, A, field);
        float* cin = A;
        float* cout = B;
        for (int k = 0; k <= 10; ++k) {
            int last = (k == 10) ? 1 : 0;
            fused_kernel<<<fgrid, fblock, 0, stream>>>(cin, cout, SK, logits, targets,
                                                       sums, k, last, field);
            float* sw = cin; cin = cout; cout = sw;
        }
    }
    final_kernel<<<1, 1, 0, stream>>>(sums, out);
}

// Round 3
// 1804.769 us; speedup vs baseline: 1.7848x; 1.0564x over previous
//
#include <hip/hip_runtime.h>

// CLDice loss, fully fused pipeline (round 3).
// Identity: with a_k = erode^k(img):
//   skel = 0
//   for k = 0..10:  delta = relu(a_k - dilate(erode(a_k)));  skel += relu(delta - skel*delta)
// One fused kernel per k. k=0 computes img from logits/targets inline (no prep pass).
// k=10 skips all writes and accumulates the two global sums instead.
// Per z-step: 2 barriers (img plane ready; s1 plane ready); dilate-of-erode is
// computed directly from the 3-slot s1 ring with OOB predication (no b plane).
// Workspace floats: [sums:16][A:N][B:N][skel:N], N = 14,155,776 (~170 MB).

#define ZD 192
#define YD 192
#define XD 192
#define NB 2
constexpr int PLANE = YD * XD;
constexpr int VOL   = ZD * PLANE;       // 7,077,888
constexpr int NTOT  = NB * VOL;

constexpr int XT = 64, YT = 8, ZCH = 24;
constexpr int IW = XT + 4, IH = YT + 4; // 68 x 12 img halo plane (+-2)
constexpr int SW = XT + 2, SH = YT + 2; // 66 x 10 s1 plane (+-1)
constexpr int NIMG = IW * IH;           // 816
constexpr int NS   = SW * SH;           // 660
#define PINF __builtin_inff()

__global__ __launch_bounds__(512)
void fused_kernel(const float* __restrict__ img_in,
                  float* __restrict__ img_out,
                  float* __restrict__ skel,
                  const float* __restrict__ logits,
                  const int* __restrict__ targets,
                  float* __restrict__ sums,
                  int kidx, int last, int field)
{
    __shared__ float simg[NIMG];
    __shared__ float s1[3][NS];
    __shared__ float red[8][2];

    const int tx = threadIdx.x, ty = threadIdx.y;
    const int tid = ty * XT + tx;
    const int xt = blockIdx.x % 3, yt = blockIdx.x / 3;
    const int x0 = xt * XT, y0 = yt * YT;
    const int z0 = blockIdx.y * ZCH;
    const int bb = blockIdx.z;
    const float* inb  = img_in  + (size_t)bb * VOL;
    float*       outb = img_out + (size_t)bb * VOL;
    float*       skb  = skel    + (size_t)bb * VOL;
    const float* lg0  = logits  + (size_t)(bb * 2) * VOL;
    const float* lg1  = lg0 + VOL;
    const int*   tgb  = targets + (size_t)bb * VOL;

    // img halo-plane load map (816 entries, <=2 per thread)
    const int r0i = tid / IW, c0i = tid % IW;
    const int l1i = tid + 512;
    const int r1i = l1i / IW, c1i = l1i % IW;
    const int gy0 = y0 - 2 + r0i, gx0 = x0 - 2 + c0i;
    const int gy1 = y0 - 2 + r1i, gx1 = x0 - 2 + c1i;
    const bool ok0 = (gy0 >= 0 && gy0 < YD && gx0 >= 0 && gx0 < XD);
    const bool ok1 = (l1i < NIMG) && (gy1 >= 0 && gy1 < YD && gx1 >= 0 && gx1 < XD);
    const int off0 = gy0 * XD + gx0, off1 = gy1 * XD + gx1;

    // s1 plane map (660 entries, <=2 per thread)
    const int e1 = tid + 512;
    const int si0 = tid / SW, sj0 = tid % SW;
    const int si1 = e1 / SW, sj1 = e1 % SW;

    // dilate-neighbor validity for this thread's output column (gy, gx)
    const int gy = y0 + ty, gx = x0 + tx;
    const bool Lv = (gx > 0), Rv = (gx < XD - 1);
    const bool Tv = (gy > 0), Bv = (gy < YD - 1);

    auto load_img = [&](int zi, int off, bool ok) -> float {
        if (zi < 0 || zi >= ZD || !ok) return PINF;
        const size_t p = (size_t)zi * PLANE + off;
        if (kidx > 0) return inb[p];
        if (field)   return (tgb[p] == 1) ? 1.f : 0.f;
        return 1.f / (1.f + expf(lg0[p] - lg1[p]));
    };

    float s2p1 = -PINF, s2p2 = -PINF;   // s2(zi-2), s2(zi-3)
    float icp1 = 0.f, icp2 = 0.f;       // img center (zi-1), (zi-2)
    float bcp1 = 0.f;                   // b center (zi-2)
    float sd = 0.f, ss = 0.f;

    // prefetch plane for s=0
    float ca0 = load_img(z0 - 2, off0, ok0);
    float ca1 = load_img(z0 - 2, off1, ok1);

    constexpr int STEPS = ZCH + 4;
    #pragma unroll 1
    for (int s = 0; s < STEPS; ++s) {
        const int zi = z0 - 2 + s;
        simg[tid] = ca0;
        if (l1i < NIMG) simg[l1i] = ca1;
        // prefetch next plane before the barrier (hides HBM latency)
        if (s + 1 < STEPS) {
            ca0 = load_img(zi + 1, off0, ok0);
            ca1 = load_img(zi + 1, off1, ok1);
        }
        __syncthreads();    // B1: simg ready
        // s1(zi) = xy-min3 of img(zi) over the 66x10 region
        float* s1w = s1[s % 3];
        {
            const float* p = simg + si0 * IW + sj0;
            float m = fminf(fminf(p[0], p[1]), p[2]);
            m = fminf(m, fminf(fminf(p[IW], p[IW + 1]), p[IW + 2]));
            m = fminf(m, fminf(fminf(p[2 * IW], p[2 * IW + 1]), p[2 * IW + 2]));
            s1w[tid] = m;
        }
        if (e1 < NS) {
            const float* p = simg + si1 * IW + sj1;
            float m = fminf(fminf(p[0], p[1]), p[2]);
            m = fminf(m, fminf(fminf(p[IW], p[IW + 1]), p[IW + 2]));
            m = fminf(m, fminf(fminf(p[2 * IW], p[2 * IW + 1]), p[2 * IW + 2]));
            s1w[e1] = m;
        }
        const float ic = simg[(ty + 2) * IW + tx + 2];
        __syncthreads();    // B2: s1 ring slot ready
        // s2(zi-1) = max over valid 3x3 of b, b = min over the 3 ring slots
        const int zb = zi - 1;
        float s2n = -PINF, bc = 0.f;
        if (s >= 2 && zb >= 0 && zb < ZD) {
            const float* q0 = s1[0];
            const float* q1 = s1[1];
            const float* q2 = s1[2];
            auto bv = [&](int si, int sj) -> float {
                const int o = si * SW + sj;
                return fminf(fminf(q0[o], q1[o]), q2[o]);
            };
            bc = bv(ty + 1, tx + 1);
            float m = bc, v;
            v = bv(ty + 1, tx);     m = fmaxf(m, Lv ? v : -PINF);
            v = bv(ty + 1, tx + 2); m = fmaxf(m, Rv ? v : -PINF);
            v = bv(ty,     tx + 1); m = fmaxf(m, Tv ? v : -PINF);
            v = bv(ty,     tx);     m = fmaxf(m, (Tv && Lv) ? v : -PINF);
            v = bv(ty,     tx + 2); m = fmaxf(m, (Tv && Rv) ? v : -PINF);
            v = bv(ty + 2, tx + 1); m = fmaxf(m, Bv ? v : -PINF);
            v = bv(ty + 2, tx);     m = fmaxf(m, (Bv && Lv) ? v : -PINF);
            v = bv(ty + 2, tx + 2); m = fmaxf(m, (Bv && Rv) ? v : -PINF);
            s2n = m;
        }
        // emit zo = zi-2
        const int zo = zi - 2;
        if (zo >= z0) {
            const float d = fmaxf(s2p2, fmaxf(s2p1, s2n));
            const float delta = fmaxf(icp2 - d, 0.f);
            const size_t idx = (size_t)zo * PLANE + gy * XD + gx;
            float sv;
            if (kidx == 0) sv = delta;
            else { const float sk = skb[idx]; sv = sk + fmaxf(delta - sk * delta, 0.f); }
            if (!last) {
                skb[idx]  = sv;
                outb[idx] = bcp1;   // a_{k+1}(zo) = b(zo)
            } else {
                float w;
                if (field == 0) {
                    w = (tgb[idx] == 1) ? 1.f : 0.f;
                } else {
                    w = 1.f / (1.f + expf(lg0[idx] - lg1[idx]));
                }
                sd += sv * w;
                ss += sv;
            }
        }
        s2p2 = s2p1; s2p1 = s2n;
        icp2 = icp1; icp1 = ic;
        bcp1 = bc;
    }

    if (last) {
        #pragma unroll
        for (int o = 32; o; o >>= 1) {
            sd += __shfl_down(sd, o, 64);
            ss += __shfl_down(ss, o, 64);
        }
        if (tx == 0) { red[ty][0] = sd; red[ty][1] = ss; }
        __syncthreads();
        if (tid == 0) {
            float a = 0.f, b2 = 0.f;
            #pragma unroll
            for (int i = 0; i < 8; ++i) { a += red[i][0]; b2 += red[i][1]; }
            atomicAdd(&sums[2 * field + 0], a);
            atomicAdd(&sums[2 * field + 1], b2);
        }
    }
}

__global__ void final_kernel(const float* __restrict__ sums, float* __restrict__ out)
{
    float tprec = (sums[0] + 1.f) / (sums[1] + 1.f);
    float tsens = (sums[2] + 1.f) / (sums[3] + 1.f);
    float cl = 2.f * tprec * tsens / (tprec + tsens + 1e-7f);
    out[0] = 1.f - cl;
}

extern "C" void kernel_launch(void* const* d_in, const int* in_sizes, int n_in,
                              void* d_out, int out_size, void* d_ws, size_t ws_size,
                              hipStream_t stream)
{
    const float* logits  = (const float*)d_in[0];
    const int*   targets = (const int*)d_in[1];
    float* out  = (float*)d_out;

    float* sums = (float*)d_ws;
    float* A    = sums + 16;
    float* B    = A + NTOT;
    float* SK   = B + NTOT;
    float* bufs[2] = { A, B };

    hipMemsetAsync(sums, 0, 16 * sizeof(float), stream);

    dim3 fgrid(3 * (YD / YT), ZD / ZCH, NB);   // (72, 8, 2) = 1152 blocks
    dim3 fblock(XT, YT, 1);                    // 512 threads

    for (int field = 0; field < 2; ++field) {
        for (int k = 0; k <= 10; ++k) {
            int last = (k == 10) ? 1 : 0;
            const float* cin = bufs[(k + 1) & 1];   // unused when k==0
            float*       cout = bufs[k & 1];
            fused_kernel<<<fgrid, fblock, 0, stream>>>(cin, cout, SK, logits, targets,
                                                       sums, k, last, field);
        }
    }
    final_kernel<<<1, 1, 0, stream>>>(sums, out);
}

// Round 4
// 1408.871 us; speedup vs baseline: 2.2863x; 1.2810x over previous
//
#include <hip/hip_runtime.h>

// CLDice loss, fused + 4x-vectorized pipeline (round 4).
// Identity: with a_k = erode^k(img):
//   skel = 0;  for k=0..10: delta = relu(a_k - dilate(erode(a_k))); skel += delta*(1-skel)
// (relu(delta - skel*delta) == delta*(1-skel) since delta,skel in [0,1].)
// One fused kernel per k; k=0 builds img inline from logits/targets; k=10 reduces.
// Each thread owns a 4-wide x-quad -> all global/LDS traffic is 16B.
// Halo is +-4 columns (quad-aligned) so every edge mask is quad-uniform.
// s1 (erode xy-min) is written -inf at xy-invalid positions => dilate needs no masks.
// Workspace floats: [sums:16][A:N][B:N][skel:N], N = 14,155,776 (~170 MB).

#define ZD 192
#define YD 192
#define XD 192
#define NB 2
constexpr int PLANE = YD * XD;
constexpr int VOL   = ZD * PLANE;
constexpr int NTOT  = NB * VOL;

constexpr int XT = 64, YT = 16, ZCH = 12;
constexpr int IW = 72, IH = YT + 4;     // img plane: 20 rows x 72 cols (halo +-2 used, +-4 stored)
constexpr int SW = 72, SH = YT + 2;     // s1/b plane: 18 rows x 72 cols (halo +-1 used)
constexpr int NIMGQ = IH * 18;          // 360 quads
constexpr int NSQ   = SH * 18;          // 324 quads
constexpr int STEPS = ZCH + 4;          // 16
#define PINF __builtin_inff()

__device__ __forceinline__ float4 vf4(float v) { return make_float4(v, v, v, v); }

template <bool K0, bool LAST, bool F1>
__global__ __launch_bounds__(256)
void fused_kernel(const float* __restrict__ img_in,
                  float* __restrict__ img_out,
                  float* __restrict__ skel,
                  const float* __restrict__ logits,
                  const int* __restrict__ targets,
                  float* __restrict__ sums)
{
    __shared__ float simg[IH * IW + 8];
    __shared__ float s1m[3][SH * SW];
    __shared__ float sb[SH * SW + 8];
    __shared__ float red[4][2];

    const int tx = threadIdx.x, ty = threadIdx.y;   // (16,16)
    const int tid = ty * 16 + tx;
    const int x0 = (blockIdx.x % 3) * XT, y0 = (blockIdx.x / 3) * YT;
    const int z0 = blockIdx.y * ZCH;
    const int bb = blockIdx.z;
    const float* inb  = img_in  + (size_t)bb * VOL;
    float*       outb = img_out + (size_t)bb * VOL;
    float*       skb  = skel    + (size_t)bb * VOL;
    const float* lg0  = logits  + (size_t)(bb * 2) * VOL;
    const float* lg1  = lg0 + VOL;
    const int*   tgb  = targets + (size_t)bb * VOL;

    // ---- img quad map (2 chunks/thread); addr in floats = 4*qi for both arrays
    int im_goff[2]; bool im_ok[2]; int im_addr[2];
    #pragma unroll
    for (int j = 0; j < 2; ++j) {
        const int qi = tid + j * 256;
        const int r = qi / 18, q = qi - r * 18;
        const int gy = y0 - 2 + r, gxb = x0 - 4 + 4 * q;
        im_addr[j] = 4 * qi;
        im_goff[j] = gy * XD + gxb;
        im_ok[j]   = (qi < NIMGQ) && gy >= 0 && gy < YD && gxb >= 0 && gxb < XD;
    }
    // ---- s1/b quad map
    int sq_addr[2], sq_q[2]; bool sq_has[2], sq_ok[2];
    #pragma unroll
    for (int j = 0; j < 2; ++j) {
        const int qi = tid + j * 256;
        const int r = qi / 18, q = qi - r * 18;
        const int gy = y0 - 1 + r, gxb = x0 - 4 + 4 * q;
        sq_addr[j] = 4 * qi;
        sq_q[j]    = q;
        sq_has[j]  = (qi < NSQ);
        sq_ok[j]   = sq_has[j] && gy >= 0 && gy < YD && gxb >= 0 && gxb < XD;
    }

    auto loadq = [&](int zi, int j) -> float4 {
        float4 v = vf4(PINF);
        if (im_ok[j] && zi >= 0 && zi < ZD) {
            const size_t p = (size_t)zi * PLANE + im_goff[j];
            if constexpr (K0) {
                if constexpr (F1) {
                    const int4 t = *(const int4*)(tgb + p);
                    v = make_float4(t.x == 1 ? 1.f : 0.f, t.y == 1 ? 1.f : 0.f,
                                    t.z == 1 ? 1.f : 0.f, t.w == 1 ? 1.f : 0.f);
                } else {
                    const float4 a = *(const float4*)(lg0 + p);
                    const float4 b = *(const float4*)(lg1 + p);
                    v = make_float4(1.f / (1.f + __expf(a.x - b.x)),
                                    1.f / (1.f + __expf(a.y - b.y)),
                                    1.f / (1.f + __expf(a.z - b.z)),
                                    1.f / (1.f + __expf(a.w - b.w)));
                }
            } else {
                v = *(const float4*)(inb + p);
            }
        }
        return v;
    };

    auto do_s1 = [&](int j, float* __restrict__ s1w) {
        if (!sq_has[j]) return;
        const int a = sq_addr[j];
        const int q = sq_q[j];
        const float* p0 = simg + a;
        float4 m = vf4(PINF);
        #pragma unroll
        for (int rr = 0; rr < 3; ++rr) {
            const float* p = p0 + rr * IW;
            const float4 A = *(const float4*)p;
            const float L = (q > 0)  ? p[-1] : PINF;
            const float R = (q < 17) ? p[4]  : PINF;
            m.x = fminf(m.x, fminf(fminf(L, A.x), A.y));
            m.y = fminf(m.y, fminf(fminf(A.x, A.y), A.z));
            m.z = fminf(m.z, fminf(fminf(A.y, A.z), A.w));
            m.w = fminf(m.w, fminf(fminf(A.z, A.w), R));
        }
        if (!sq_ok[j]) m = vf4(-PINF);   // xy-invalid => dilate ignores, b stays -inf
        *(float4*)(s1w + a) = m;
    };

    auto do_b = [&](int j) {
        if (!sq_has[j]) return;
        const int a = sq_addr[j];
        const float4 u = *(const float4*)(s1m[0] + a);
        const float4 v = *(const float4*)(s1m[1] + a);
        const float4 w = *(const float4*)(s1m[2] + a);
        float4 m;
        m.x = fminf(u.x, fminf(v.x, w.x));
        m.y = fminf(u.y, fminf(v.y, w.y));
        m.z = fminf(u.z, fminf(v.z, w.z));
        m.w = fminf(u.w, fminf(v.w, w.w));
        *(float4*)(sb + a) = m;
    };

    float4 s2p1 = vf4(-PINF), s2p2 = vf4(-PINF);
    float4 icp1 = vf4(0.f), icp2 = vf4(0.f), bcp1 = vf4(0.f);
    float sd = 0.f, ss = 0.f;

    float4 ca0 = loadq(z0 - 2, 0);
    float4 ca1 = loadq(z0 - 2, 1);

    #pragma unroll 1
    for (int s = 0; s < STEPS; ++s) {
        const int zi = z0 - 2 + s;
        *(float4*)(simg + im_addr[0]) = ca0;
        if (tid < NIMGQ - 256) *(float4*)(simg + im_addr[1]) = ca1;
        if (s + 1 < STEPS) { ca0 = loadq(zi + 1, 0); ca1 = loadq(zi + 1, 1); }
        __syncthreads();                          // B1: simg ready
        float* s1w = s1m[s % 3];
        do_s1(0, s1w);
        do_s1(1, s1w);
        const float4 icq = *(const float4*)(simg + (ty + 2) * IW + 4 + 4 * tx);
        __syncthreads();                          // B2: s1 slot ready (and simg reads done)
        const int zb = zi - 1;
        const bool zbv = (s >= 2) && (zb >= 0) && (zb < ZD);
        if (zbv) { do_b(0); do_b(1); }
        __syncthreads();                          // B3: b plane ready
        float4 s2n = vf4(-PINF), bcq = vf4(0.f);
        if (zbv) {
            const int cb = ty * SW + 4 + 4 * tx;
            #pragma unroll
            for (int rr = 0; rr < 3; ++rr) {
                const float* p = sb + cb + rr * SW;
                const float4 B = *(const float4*)p;
                const float L = p[-1], R = p[4];
                s2n.x = fmaxf(s2n.x, fmaxf(fmaxf(L, B.x), B.y));
                s2n.y = fmaxf(s2n.y, fmaxf(fmaxf(B.x, B.y), B.z));
                s2n.z = fmaxf(s2n.z, fmaxf(fmaxf(B.y, B.z), B.w));
                s2n.w = fmaxf(s2n.w, fmaxf(fmaxf(B.z, B.w), R));
                if (rr == 1) bcq = B;
            }
        }
        const int zo = zi - 2;
        if (zo >= z0) {
            float4 d;
            d.x = fmaxf(s2p2.x, fmaxf(s2p1.x, s2n.x));
            d.y = fmaxf(s2p2.y, fmaxf(s2p1.y, s2n.y));
            d.z = fmaxf(s2p2.z, fmaxf(s2p1.z, s2n.z));
            d.w = fmaxf(s2p2.w, fmaxf(s2p1.w, s2n.w));
            float4 dl;
            dl.x = fmaxf(icp2.x - d.x, 0.f);
            dl.y = fmaxf(icp2.y - d.y, 0.f);
            dl.z = fmaxf(icp2.z - d.z, 0.f);
            dl.w = fmaxf(icp2.w - d.w, 0.f);
            const size_t idx = (size_t)zo * PLANE + (size_t)(y0 + ty) * XD + (x0 + 4 * tx);
            float4 sv;
            if constexpr (K0) {
                sv = dl;
            } else {
                const float4 sk = *(const float4*)(skb + idx);
                sv.x = sk.x + dl.x * (1.f - sk.x);
                sv.y = sk.y + dl.y * (1.f - sk.y);
                sv.z = sk.z + dl.z * (1.f - sk.z);
                sv.w = sk.w + dl.w * (1.f - sk.w);
            }
            if constexpr (!LAST) {
                *(float4*)(skb + idx)  = sv;
                *(float4*)(outb + idx) = bcp1;    // a_{k+1}(zo) = b(zo)
            } else {
                float4 w;
                if constexpr (F1) {               // gt skeleton weighted by pred
                    const float4 a = *(const float4*)(lg0 + idx);
                    const float4 b = *(const float4*)(lg1 + idx);
                    w = make_float4(1.f / (1.f + __expf(a.x - b.x)),
                                    1.f / (1.f + __expf(a.y - b.y)),
                                    1.f / (1.f + __expf(a.z - b.z)),
                                    1.f / (1.f + __expf(a.w - b.w)));
                } else {                          // pred skeleton weighted by gt
                    const int4 t = *(const int4*)(tgb + idx);
                    w = make_float4(t.x == 1 ? 1.f : 0.f, t.y == 1 ? 1.f : 0.f,
                                    t.z == 1 ? 1.f : 0.f, t.w == 1 ? 1.f : 0.f);
                }
                sd += sv.x * w.x + sv.y * w.y + sv.z * w.z + sv.w * w.w;
                ss += sv.x + sv.y + sv.z + sv.w;
            }
        }
        s2p2 = s2p1; s2p1 = s2n;
        icp2 = icp1; icp1 = icq;
        bcp1 = bcq;
    }

    if constexpr (LAST) {
        #pragma unroll
        for (int o = 32; o; o >>= 1) {
            sd += __shfl_down(sd, o, 64);
            ss += __shfl_down(ss, o, 64);
        }
        const int w = tid >> 6;
        if ((tid & 63) == 0) { red[w][0] = sd; red[w][1] = ss; }
        __syncthreads();
        if (tid == 0) {
            float a = 0.f, b = 0.f;
            #pragma unroll
            for (int i = 0; i < 4; ++i) { a += red[i][0]; b += red[i][1]; }
            const int f = F1 ? 1 : 0;
            atomicAdd(&sums[2 * f + 0], a);
            atomicAdd(&sums[2 * f + 1], b);
        }
    }
}

__global__ void final_kernel(const float* __restrict__ sums, float* __restrict__ out)
{
    float tprec = (sums[0] + 1.f) / (sums[1] + 1.f);
    float tsens = (sums[2] + 1.f) / (sums[3] + 1.f);
    float cl = 2.f * tprec * tsens / (tprec + tsens + 1e-7f);
    out[0] = 1.f - cl;
}

extern "C" void kernel_launch(void* const* d_in, const int* in_sizes, int n_in,
                              void* d_out, int out_size, void* d_ws, size_t ws_size,
                              hipStream_t stream)
{
    const float* logits  = (const float*)d_in[0];
    const int*   targets = (const int*)d_in[1];
    float* out  = (float*)d_out;

    float* sums = (float*)d_ws;
    float* A    = sums + 16;
    float* B    = A + NTOT;
    float* SK   = B + NTOT;
    float* bufs[2] = { A, B };

    hipMemsetAsync(sums, 0, 16 * sizeof(float), stream);

    dim3 fgrid(3 * (YD / YT), ZD / ZCH, NB);   // (36, 16, 2) = 1152 blocks
    dim3 fblock(16, 16, 1);                    // 256 threads, x-quads

    for (int field = 0; field < 2; ++field) {
        for (int k = 0; k <= 10; ++k) {
            const float* cin = bufs[(k + 1) & 1];
            float*       cout = bufs[k & 1];
            if (k == 0) {
                if (field) fused_kernel<true , false, true ><<<fgrid, fblock, 0, stream>>>(cin, cout, SK, logits, targets, sums);
                else       fused_kernel<true , false, false><<<fgrid, fblock, 0, stream>>>(cin, cout, SK, logits, targets, sums);
            } else if (k < 10) {
                if (field) fused_kernel<false, false, true ><<<fgrid, fblock, 0, stream>>>(cin, cout, SK, logits, targets, sums);
                else       fused_kernel<false, false, false><<<fgrid, fblock, 0, stream>>>(cin, cout, SK, logits, targets, sums);
            } else {
                if (field) fused_kernel<false, true , true ><<<fgrid, fblock, 0, stream>>>(cin, cout, SK, logits, targets, sums);
                else       fused_kernel<false, true , false><<<fgrid, fblock, 0, stream>>>(cin, cout, SK, logits, targets, sums);
            }
        }
    }
    final_kernel<<<1, 1, 0, stream>>>(sums, out);
}

// Round 5
// 1378.010 us; speedup vs baseline: 2.3375x; 1.0224x over previous
//
#include <hip/hip_runtime.h>

// CLDice loss, round 5: register-ring erode + shifted-b LDS + all-b128 stencils.
// Identity: with a_k = erode^k(img):
//   skel = 0;  for k=0..10: delta = relu(a_k - dilate(erode(a_k))); skel += delta*(1-skel)
// One fused kernel per k; k=0 builds img inline; k=10 reduces instead of writing.
// Per z-step (2 barriers):
//   B1: img plane (double-buffered) staged to LDS (quad-aligned, halo +-4 cols, +-2 rows)
//   erode xy-min via 2 aligned b128 reads/row (offset windows), z-min in a
//   private 2-register ring -> b plane written to LDS *shifted by -1 column*
//   B2: dilate xy-max via 2 aligned b128 reads/row from shifted b; z-max in registers.
// No scalar LDS reads anywhere -> no bank conflicts.
// Workspace floats: [sums:16][A:N][B:N][skel:N], N = 14,155,776 (~170 MB).

#define ZD 192
#define YD 192
#define XD 192
#define NB 2
constexpr int PLANE = YD * XD;
constexpr int VOL   = ZD * PLANE;
constexpr int NTOT  = NB * VOL;

constexpr int XT = 64, YT = 16, ZCH = 12;
constexpr int IH = YT + 4, IWQ = 18;     // img: 20 rows x 18 quads (x halo +-4, y halo +-2)
constexpr int BH = YT + 2, BWQ = 17;     // b:   18 rows x 17 quads, shifted -1 col
constexpr int NIMGQ = IH * IWQ;          // 360
constexpr int NBQ   = BH * BWQ;          // 306
constexpr int STEPS = ZCH + 4;           // 16
#define PINF __builtin_inff()

__device__ __forceinline__ float4 vf4(float v) { return make_float4(v, v, v, v); }
__device__ __forceinline__ float4 vmin(float4 a, float4 b) {
    return make_float4(fminf(a.x, b.x), fminf(a.y, b.y), fminf(a.z, b.z), fminf(a.w, b.w));
}
__device__ __forceinline__ float4 vmax(float4 a, float4 b) {
    return make_float4(fmaxf(a.x, b.x), fmaxf(a.y, b.y), fmaxf(a.z, b.z), fmaxf(a.w, b.w));
}

template <bool K0, bool LAST, bool F1>
__global__ __launch_bounds__(256)
void fused_kernel(const float* __restrict__ img_in,
                  float* __restrict__ img_out,
                  float* __restrict__ skel,
                  const float* __restrict__ logits,
                  const int* __restrict__ targets,
                  float* __restrict__ sums)
{
    __shared__ float simg[2][NIMGQ * 4];
    __shared__ float sbp[NBQ * 4];
    __shared__ float red[4][2];

    const int tx = threadIdx.x, ty = threadIdx.y;   // (16,16)
    const int tid = ty * 16 + tx;
    const int x0 = (blockIdx.x % 3) * XT, y0 = (blockIdx.x / 3) * YT;
    const int z0 = blockIdx.y * ZCH;
    const int bb = blockIdx.z;
    const float* inb  = img_in  + (size_t)bb * VOL;
    float*       outb = img_out + (size_t)bb * VOL;
    float*       skb  = skel    + (size_t)bb * VOL;
    const float* lg0  = logits  + (size_t)(bb * 2) * VOL;
    const float* lg1  = lg0 + VOL;
    const int*   tgb  = targets + (size_t)bb * VOL;

    const int q1off = ((tid & 3) << 6) + (tid >> 2);  // balanced 2nd-chunk id

    // ---- img chunks (aligned quads, base x0-4, y0-2)
    int im_qi[2] = { tid, 256 + q1off };
    int im_goff[2]; bool im_ok[2], im_has[2];
    #pragma unroll
    for (int j = 0; j < 2; ++j) {
        const int qi = im_qi[j];
        const int r = qi / IWQ, c = qi - r * IWQ;
        const int gy = y0 - 2 + r, gxb = x0 - 4 + 4 * c;
        im_has[j] = (qi < NIMGQ);
        im_ok[j]  = im_has[j] && gy >= 0 && gy < YD && gxb >= 0 && gxb < XD;
        im_goff[j] = gy * XD + gxb;
    }

    // ---- b chunks (shifted quads: slot (r,j) holds x = x0-1+4j+e, y = y0-1+r)
    int bqi[2]; bool bhas[2]; int brow[2], bcol[2]; float4 bmask[2];
    #pragma unroll
    for (int j = 0; j < 2; ++j) {
        const int qi = (j == 0) ? tid : 256 + q1off;
        bqi[j] = qi;
        bhas[j] = (qi < NBQ);
        const int r = qi / BWQ, c = qi - r * BWQ;
        brow[j] = r; bcol[j] = c;
        const int gy = y0 - 1 + r, gxb = x0 - 1 + 4 * c;
        const bool yv = (gy >= 0 && gy < YD);
        float4 m;
        m.x = (yv && gxb     >= 0 && gxb     < XD) ? PINF : -PINF;
        m.y = (yv && gxb + 1 >= 0 && gxb + 1 < XD) ? PINF : -PINF;
        m.z = (yv && gxb + 2 >= 0 && gxb + 2 < XD) ? PINF : -PINF;
        m.w = (yv && gxb + 3 >= 0 && gxb + 3 < XD) ? PINF : -PINF;
        bmask[j] = m;
    }

    auto loadq = [&](int zi, int j) -> float4 {
        float4 v = vf4(PINF);
        if (im_ok[j] && zi >= 0 && zi < ZD) {
            const size_t p = (size_t)zi * PLANE + im_goff[j];
            if constexpr (K0) {
                if constexpr (F1) {
                    const int4 t = *(const int4*)(tgb + p);
                    v = make_float4(t.x == 1 ? 1.f : 0.f, t.y == 1 ? 1.f : 0.f,
                                    t.z == 1 ? 1.f : 0.f, t.w == 1 ? 1.f : 0.f);
                } else {
                    const float4 a = *(const float4*)(lg0 + p);
                    const float4 b = *(const float4*)(lg1 + p);
                    v = make_float4(1.f / (1.f + __expf(a.x - b.x)),
                                    1.f / (1.f + __expf(a.y - b.y)),
                                    1.f / (1.f + __expf(a.z - b.z)),
                                    1.f / (1.f + __expf(a.w - b.w)));
                }
            } else {
                v = *(const float4*)(inb + p);
            }
        }
        return v;
    };

    // erode xy-min for b slot (r,j): img rows r..r+2, aligned quads j, j+1.
    auto s1_of = [&](const float* sp, int j) -> float4 {
        const float* p = sp + brow[j] * (IWQ * 4) + 4 * bcol[j];
        const float4 A0 = *(const float4*)p;
        const float4 B0 = *(const float4*)(p + 4);
        const float4 A1 = *(const float4*)(p + IWQ * 4);
        const float4 B1 = *(const float4*)(p + IWQ * 4 + 4);
        const float4 A2 = *(const float4*)(p + IWQ * 8);
        const float4 B2 = *(const float4*)(p + IWQ * 8 + 4);
        const float az = fminf(A0.z, fminf(A1.z, A2.z));
        const float aw = fminf(A0.w, fminf(A1.w, A2.w));
        const float4 Br = vmin(B0, vmin(B1, B2));
        const float t1 = fminf(aw, Br.x);
        const float t2 = fminf(Br.y, Br.z);
        float4 m;
        m.x = fminf(az, t1);
        m.y = fminf(t1, Br.y);
        m.z = fminf(Br.x, t2);
        m.w = fminf(t2, Br.w);
        return m;
    };

    float4 p2a = vf4(PINF), p1a = vf4(PINF);   // s1 ring chunk0
    float4 p2b = vf4(PINF), p1b = vf4(PINF);   // s1 ring chunk1
    float4 s2p1 = vf4(-PINF), s2p2 = vf4(-PINF);
    float4 icp1 = vf4(0.f), icp2 = vf4(0.f), bcp1 = vf4(0.f);
    float sd = 0.f, ss = 0.f;

    float4 ca0 = loadq(z0 - 2, 0);
    float4 ca1 = loadq(z0 - 2, 1);

    #pragma unroll 2
    for (int s = 0; s < STEPS; ++s) {
        const int zi = z0 - 2 + s;
        float* sp = simg[s & 1];
        *(float4*)(sp + 4 * im_qi[0]) = ca0;
        if (im_has[1]) *(float4*)(sp + 4 * im_qi[1]) = ca1;
        if (s + 1 < STEPS) { ca0 = loadq(zi + 1, 0); ca1 = loadq(zi + 1, 1); }
        __syncthreads();                        // B1: simg[s&1] ready
        const int zb = zi - 1;
        const bool zbv = (s >= 2) && (zb >= 0) && (zb < ZD);
        {
            const float4 cur = s1_of(sp, 0);
            if (zbv) {
                float4 b = vmin(vmin(p2a, p1a), cur);
                b = vmin(b, bmask[0]);
                *(float4*)(sbp + 4 * bqi[0]) = b;
            }
            p2a = p1a; p1a = cur;
        }
        if (bhas[1]) {
            const float4 cur = s1_of(sp, 1);
            if (zbv) {
                float4 b = vmin(vmin(p2b, p1b), cur);
                b = vmin(b, bmask[1]);
                *(float4*)(sbp + 4 * bqi[1]) = b;
            }
            p2b = p1b; p1b = cur;
        }
        const float4 icq = *(const float4*)(sp + (ty + 2) * (IWQ * 4) + 4 * (tx + 1));
        __syncthreads();                        // B2: b plane ready
        // dilate xy-max at output quad (tx, ty) from shifted b, rows ty..ty+2
        float4 s2n = vf4(-PINF), bcq = vf4(0.f);
        if (zbv) {
            const float* p = sbp + (ty * BWQ + tx) * 4;
            const float4 U0 = *(const float4*)p;
            const float4 V0 = *(const float4*)(p + 4);
            const float4 U1 = *(const float4*)(p + BWQ * 4);
            const float4 V1 = *(const float4*)(p + BWQ * 4 + 4);
            const float4 U2 = *(const float4*)(p + BWQ * 8);
            const float4 V2 = *(const float4*)(p + BWQ * 8 + 4);
            bcq = make_float4(U1.y, U1.z, U1.w, V1.x);     // b at the output quad
            const float4 Ur = vmax(U0, vmax(U1, U2));
            const float vx = fmaxf(V0.x, fmaxf(V1.x, V2.x));
            const float vy = fmaxf(V0.y, fmaxf(V1.y, V2.y));
            const float t1 = fmaxf(Ur.y, Ur.z);
            const float t2 = fmaxf(Ur.w, vx);
            s2n.x = fmaxf(Ur.x, t1);
            s2n.y = fmaxf(t1, Ur.w);
            s2n.z = fmaxf(Ur.z, t2);
            s2n.w = fmaxf(t2, vy);
        }
        // emit zo = zi-2
        if (s >= 4) {
            const int zo = zi - 2;
            const float4 d = vmax(s2p2, vmax(s2p1, s2n));
            float4 dl;
            dl.x = fmaxf(icp2.x - d.x, 0.f);
            dl.y = fmaxf(icp2.y - d.y, 0.f);
            dl.z = fmaxf(icp2.z - d.z, 0.f);
            dl.w = fmaxf(icp2.w - d.w, 0.f);
            const size_t idx = (size_t)zo * PLANE + (size_t)(y0 + ty) * XD + (x0 + 4 * tx);
            float4 sv;
            if constexpr (K0) {
                sv = dl;
            } else {
                const float4 sk = *(const float4*)(skb + idx);
                sv.x = sk.x + dl.x * (1.f - sk.x);
                sv.y = sk.y + dl.y * (1.f - sk.y);
                sv.z = sk.z + dl.z * (1.f - sk.z);
                sv.w = sk.w + dl.w * (1.f - sk.w);
            }
            if constexpr (!LAST) {
                *(float4*)(skb + idx)  = sv;
                *(float4*)(outb + idx) = bcp1;    // a_{k+1}(zo) = b(zo)
            } else {
                float4 w;
                if constexpr (F1) {               // gt skeleton weighted by pred
                    const float4 a = *(const float4*)(lg0 + idx);
                    const float4 b = *(const float4*)(lg1 + idx);
                    w = make_float4(1.f / (1.f + __expf(a.x - b.x)),
                                    1.f / (1.f + __expf(a.y - b.y)),
                                    1.f / (1.f + __expf(a.z - b.z)),
                                    1.f / (1.f + __expf(a.w - b.w)));
                } else {                          // pred skeleton weighted by gt
                    const int4 t = *(const int4*)(tgb + idx);
                    w = make_float4(t.x == 1 ? 1.f : 0.f, t.y == 1 ? 1.f : 0.f,
                                    t.z == 1 ? 1.f : 0.f, t.w == 1 ? 1.f : 0.f);
                }
                sd += sv.x * w.x + sv.y * w.y + sv.z * w.z + sv.w * w.w;
                ss += sv.x + sv.y + sv.z + sv.w;
            }
        }
        s2p2 = s2p1; s2p1 = s2n;
        icp2 = icp1; icp1 = icq;
        bcp1 = bcq;
    }

    if constexpr (LAST) {
        #pragma unroll
        for (int o = 32; o; o >>= 1) {
            sd += __shfl_down(sd, o, 64);
            ss += __shfl_down(ss, o, 64);
        }
        const int w = tid >> 6;
        if ((tid & 63) == 0) { red[w][0] = sd; red[w][1] = ss; }
        __syncthreads();
        if (tid == 0) {
            float a = 0.f, b = 0.f;
            #pragma unroll
            for (int i = 0; i < 4; ++i) { a += red[i][0]; b += red[i][1]; }
            const int f = F1 ? 1 : 0;
            atomicAdd(&sums[2 * f + 0], a);
            atomicAdd(&sums[2 * f + 1], b);
        }
    }
}

__global__ void final_kernel(const float* __restrict__ sums, float* __restrict__ out)
{
    float tprec = (sums[0] + 1.f) / (sums[1] + 1.f);
    float tsens = (sums[2] + 1.f) / (sums[3] + 1.f);
    float cl = 2.f * tprec * tsens / (tprec + tsens + 1e-7f);
    out[0] = 1.f - cl;
}

extern "C" void kernel_launch(void* const* d_in, const int* in_sizes, int n_in,
                              void* d_out, int out_size, void* d_ws, size_t ws_size,
                              hipStream_t stream)
{
    const float* logits  = (const float*)d_in[0];
    const int*   targets = (const int*)d_in[1];
    float* out  = (float*)d_out;

    float* sums = (float*)d_ws;
    float* A    = sums + 16;
    float* B    = A + NTOT;
    float* SK   = B + NTOT;
    float* bufs[2] = { A, B };

    hipMemsetAsync(sums, 0, 16 * sizeof(float), stream);

    dim3 fgrid(3 * (YD / YT), ZD / ZCH, NB);   // (36, 16, 2) = 1152 blocks
    dim3 fblock(16, 16, 1);                    // 256 threads, x-quads

    for (int field = 0; field < 2; ++field) {
        for (int k = 0; k <= 10; ++k) {
            const float* cin = bufs[(k + 1) & 1];
            float*       cout = bufs[k & 1];
            if (k == 0) {
                if (field) fused_kernel<true , false, true ><<<fgrid, fblock, 0, stream>>>(cin, cout, SK, logits, targets, sums);
                else       fused_kernel<true , false, false><<<fgrid, fblock, 0, stream>>>(cin, cout, SK, logits, targets, sums);
            } else if (k < 10) {
                if (field) fused_kernel<false, false, true ><<<fgrid, fblock, 0, stream>>>(cin, cout, SK, logits, targets, sums);
                else       fused_kernel<false, false, false><<<fgrid, fblock, 0, stream>>>(cin, cout, SK, logits, targets, sums);
            } else {
                if (field) fused_kernel<false, true , true ><<<fgrid, fblock, 0, stream>>>(cin, cout, SK, logits, targets, sums);
                else       fused_kernel<false, true , false><<<fgrid, fblock, 0, stream>>>(cin, cout, SK, logits, targets, sums);
            }
        }
    }
    final_kernel<<<1, 1, 0, stream>>>(sums, out);
}